// Round 5
// baseline (214.876 us; speedup 1.0000x reference)
//
#include <hip/hip_runtime.h>
#include <math.h>

#define B_  4
#define C1_ 256
#define C2_ 256
#define H_  64
#define W_  64
#define HW_ 4096
#define KK_ 9

// ws byte offsets
#define WA_OFF    0u            // bf16 Wa[72][4][256][8]          (1,179,648 B)
#define MIDX_OFF  1179648u      // int4  midx[B][9][4096]          (2,359,296 B)
#define MWGT_OFF  3538944u      // float4 mwgt[B][9][4096]         (2,359,296 B)
#define WOM_OFF   5898240u      // bf16 Wom[72][4][32][8]          (147,456 B)
#define BN_OFF    6045696u      // float inv[256]; bb[256]         (2,048 B)

typedef short bf16x8 __attribute__((ext_vector_type(8)));
typedef float f32x4 __attribute__((ext_vector_type(4)));

__device__ __forceinline__ unsigned f2bfu(float f) {
  unsigned u = __builtin_bit_cast(unsigned, f);
  return (u + 0x7FFFu + ((u >> 16) & 1u)) >> 16;
}

__device__ __forceinline__ void gload_lds16(const void* g, void* l) {
  __builtin_amdgcn_global_load_lds(
      (const __attribute__((address_space(1))) unsigned*)g,
      (__attribute__((address_space(3))) unsigned*)l, 16, 0, 0);
}

// XCD-aware decode: 256 blocks, 8 XCDs (bid%8 = xcd). Each XCD gets 32
// consecutive rows of ONE batch -> x slice ~2.2 MB fits per-XCD 4 MB L2.
__device__ __forceinline__ void decode_bid(int bid, int& b, int& h) {
  const int xcd = bid & 7, slot = bid >> 3;
  b = xcd >> 1;
  h = (xcd & 1) * 32 + slot;
}

// ---------------------------------------------------------------------------
// wom_perm: w_om [27][C1][9] -> Wom bf16 [72 kt][4 kg][32 o][8 j], ck=k*256+c,
// o padded 27->32 with zeros. Block 0 also precomputes BN inv/bb.
// ---------------------------------------------------------------------------
__global__ __launch_bounds__(256) void wom_perm(
    const float* __restrict__ w_om, const float* __restrict__ bn_gamma,
    const float* __restrict__ bn_beta, const float* __restrict__ bn_mean,
    const float* __restrict__ bn_var, char* __restrict__ wsb) {
  if (blockIdx.x == 0) {
    const int o = threadIdx.x;
    float inv = bn_gamma[o] * rsqrtf(bn_var[o] + 1e-5f);
    ((float*)(wsb + BN_OFF))[o] = inv;
    ((float*)(wsb + BN_OFF))[256 + o] = bn_beta[o] - bn_mean[o] * inv;
  }
  const unsigned e = blockIdx.x * 256 + threadIdx.x;  // < 73728
  const unsigned kt = e >> 10, kg = (e >> 8) & 3, o = (e >> 3) & 31, j = e & 7;
  const unsigned ck = kt * 32 + kg * 8 + j;
  const unsigned k = ck >> 8, c = ck & 255;
  const float v = (o < 27) ? w_om[((size_t)o * C1_ + c) * 9 + k] : 0.f;
  ((unsigned short*)(wsb + WOM_OFF))[e] = (unsigned short)f2bfu(v);
}

// ---------------------------------------------------------------------------
// wt_perm: w_dcn [C2][C1][9] -> Wa bf16 [72 kt][4 kg][256 o][8 j], ck=k*256+c.
// ---------------------------------------------------------------------------
__global__ __launch_bounds__(256) void wt_perm(const float* __restrict__ w_dcn,
                                               char* __restrict__ wsb) {
  const unsigned e = blockIdx.x * 256 + threadIdx.x;  // < 589824
  const unsigned kt = e >> 13, r2 = e & 8191;
  const unsigned kg = r2 >> 11, r3 = r2 & 2047, o = r3 >> 3, j = r3 & 7;
  const unsigned ck = kt * 32 + kg * 8 + j;
  const unsigned k = ck >> 8, c = ck & 255;
  const float v = w_dcn[((size_t)o * C1_ + c) * 9 + k];
  ((unsigned short*)(wsb + WA_OFF))[e] = (unsigned short)f2bfu(v);
}

// ---------------------------------------------------------------------------
// om_gemm: om[oc,p] = sum_ck Wom[ck,oc] * im2col(x)[ck,p] (MFMA), then fused
// epilogue: bias + clamp/sigmoid -> bilinear meta (idx + premult weights).
// Block: O=32 x P=64, 256 thr = 4 waves; grid = 256 (XCD-swizzled (b,h)).
// ---------------------------------------------------------------------------
__global__ __launch_bounds__(256) void om_gemm(const float* __restrict__ x,
                                               const float* __restrict__ b_om,
                                               char* __restrict__ wsb) {
  __shared__ short Ald[2][1024];  // [buf][kg4][o32][j8]
  __shared__ short Bld[2][2048];  // [buf][kg4][p64][j8]
  __shared__ float omld[32][65];

  int b, h;
  decode_bid(blockIdx.x, b, h);
  const int tid = threadIdx.x;
  const int lane = tid & 63, wid = tid >> 6;
  const int wo = wid >> 1, wp = wid & 1;
  const int w = tid & 63;
  const int cr = tid >> 6;

  const unsigned short* Wom = (const unsigned short*)(wsb + WOM_OFF);
  const float* xb = x + (size_t)b * C1_ * HW_;

  f32x4 acc[2];
#pragma unroll
  for (int j = 0; j < 2; ++j) acc[j] = (f32x4){0.f, 0.f, 0.f, 0.f};

  auto stageA = [&](int kt, int buf) {
    if (tid < 128)
      gload_lds16((const char*)(Wom + (size_t)kt * 1024) + tid * 16,
                  (char*)&Ald[buf][0] + tid * 16);
  };

  auto produce = [&](int kt, int4& pk) {
    const int k = kt >> 3;
    const int c0 = (kt & 7) * 32 + cr * 8;
    const int hh = h - 1 + k / 3, ww = w - 1 + k % 3;
    const bool v = ((unsigned)hh < (unsigned)H_) && ((unsigned)ww < (unsigned)W_);
    const float* pl = xb + (size_t)c0 * HW_ + (v ? hh * W_ + ww : 0);
    unsigned bf[8];
#pragma unroll
    for (int i = 0; i < 8; ++i) {
      float t = v ? pl[(size_t)i * HW_] : 0.f;
      bf[i] = f2bfu(t);
    }
    pk.x = bf[0] | (bf[1] << 16);
    pk.y = bf[2] | (bf[3] << 16);
    pk.z = bf[4] | (bf[5] << 16);
    pk.w = bf[6] | (bf[7] << 16);
  };

  const int bslot = cr * 512 + w * 8;

  auto compute = [&](int buf) {
    const int kg = lane >> 4, rr = lane & 15;
    bf16x8 af = *(const bf16x8*)&Ald[buf][kg * 256 + (wo * 16 + rr) * 8];
#pragma unroll
    for (int fn = 0; fn < 2; ++fn) {
      bf16x8 bfr =
          *(const bf16x8*)&Bld[buf][kg * 512 + (wp * 32 + fn * 16 + rr) * 8];
      acc[fn] = __builtin_amdgcn_mfma_f32_16x16x32_bf16(af, bfr, acc[fn], 0, 0, 0);
    }
  };

  {
    int4 pk;
    stageA(0, 0);
    produce(0, pk);
    *(int4*)&Bld[0][bslot] = pk;
  }
  __syncthreads();

  auto iter = [&](int kt, int buf) {
    const int nxt = buf ^ 1;
    int4 pk;
    const bool pre = (kt < 71);
    if (pre) {
      stageA(kt + 1, nxt);
      produce(kt + 1, pk);
    }
    compute(buf);
    if (pre) *(int4*)&Bld[nxt][bslot] = pk;
    __syncthreads();
  };

  for (int kt = 0; kt < 72; kt += 2) {
    iter(kt, 0);
    iter(kt + 1, 1);
  }

  // stash om tile to LDS (transpose to per-column access)
  {
    const int rr = lane & 15, rh = lane >> 4;
#pragma unroll
    for (int r = 0; r < 4; ++r) {
      const int oc = wo * 16 + rh * 4 + r;
#pragma unroll
      for (int fn = 0; fn < 2; ++fn) {
        const int p = wp * 32 + fn * 16 + rr;
        omld[oc][p] = acc[fn][r];
      }
    }
  }
  __syncthreads();

  // fused om_final: one thread per column p
  if (tid < 64) {
    const int p = tid;
    float a[27];
#pragma unroll
    for (int oc = 0; oc < 27; ++oc) a[oc] = omld[oc][p] + b_om[oc];

    int4* midx = (int4*)(wsb + MIDX_OFF);
    float4* mwgt = (float4*)(wsb + MWGT_OFF);
#pragma unroll
    for (int k = 0; k < 9; ++k) {
      float dy = fminf(fmaxf(a[2 * k], -6.f), 6.f);
      float dx = fminf(fmaxf(a[2 * k + 1], -6.f), 6.f);
      float m = 1.f / (1.f + expf(-a[18 + k]));
      float py = (float)(h - 1 + k / 3) + dy;
      float px = (float)(p - 1 + k % 3) + dx;
      float y0f = floorf(py), x0f = floorf(px);
      float ly = py - y0f, lx = px - x0f;
      int y0 = (int)y0f, x0 = (int)x0f;
      int y1 = y0 + 1, x1 = x0 + 1;
      const bool vy0 = ((unsigned)y0 < (unsigned)H_);
      const bool vy1 = ((unsigned)y1 < (unsigned)H_);
      const bool vx0 = ((unsigned)x0 < (unsigned)W_);
      const bool vx1 = ((unsigned)x1 < (unsigned)W_);
      int y0c = min(max(y0, 0), H_ - 1), y1c = min(max(y1, 0), H_ - 1);
      int x0c = min(max(x0, 0), W_ - 1), x1c = min(max(x1, 0), W_ - 1);
      const size_t e = ((size_t)b * KK_ + k) * HW_ + h * W_ + p;
      midx[e] = make_int4(y0c * W_ + x0c, y0c * W_ + x1c, y1c * W_ + x0c,
                          y1c * W_ + x1c);
      mwgt[e] = make_float4((1.f - ly) * (1.f - lx) * ((vy0 && vx0) ? m : 0.f),
                            (1.f - ly) * lx * ((vy0 && vx1) ? m : 0.f),
                            ly * (1.f - lx) * ((vy1 && vx0) ? m : 0.f),
                            ly * lx * ((vy1 && vx1) ? m : 0.f));
    }
  }
}

// ---------------------------------------------------------------------------
// dcn_mfma: out[o,p] = sum_ck Wa[ck,o] * col[ck,p], fused BN+SiLU.
// Block: O=256 x P=64 (one row), 512 thr = 8 waves (wave 64o x 32p).
// 72 kt-steps of BK=32, double-buffered LDS, producer gathers prefetched
// 2 kt-steps ahead in registers. grid = 256, XCD-swizzled (b,h).
// ---------------------------------------------------------------------------
__global__ __launch_bounds__(512) void dcn_mfma(const float* __restrict__ x,
                                                const char* __restrict__ wsb,
                                                float* __restrict__ out) {
  __shared__ short Ald[2][8192];  // [buf][kg4][o256][j8]
  __shared__ short Bld[2][2048];  // [buf][kg4][p64][j8]

  int b, pt;
  decode_bid(blockIdx.x, b, pt);
  const int tid = threadIdx.x;
  const int lane = tid & 63, wid = tid >> 6;
  const int wo = wid >> 1, wp = wid & 1;
  const int p = tid & 63;   // producer column
  const int cr = tid >> 6;  // producer ck-subrange (4 ch each)

  const unsigned short* Wa = (const unsigned short*)(wsb + WA_OFF);
  const int4* midx =
      (const int4*)(wsb + MIDX_OFF) + (size_t)b * KK_ * HW_ + pt * 64 + p;
  const float4* mwgt =
      (const float4*)(wsb + MWGT_OFF) + (size_t)b * KK_ * HW_ + pt * 64 + p;
  const float* xb = x + (size_t)b * C1_ * HW_;

  f32x4 acc[4][2];
#pragma unroll
  for (int i = 0; i < 4; ++i)
#pragma unroll
    for (int j = 0; j < 2; ++j) acc[i][j] = (f32x4){0.f, 0.f, 0.f, 0.f};

  int4 miR[2];
  float4 mwR[2];

  auto stageA = [&](int kt, int buf) {
    const char* src = (const char*)(Wa + (size_t)kt * 8192);
#pragma unroll
    for (int r = 0; r < 2; ++r) {
      const int chunk = r * 512 + tid;
      gload_lds16(src + chunk * 16, (char*)&Ald[buf][0] + chunk * 16);
    }
  };

  // issue raw gathers for step kt into rg[16]
  auto issue = [&](int kt, float (&rg)[16]) {
    const int k = kt >> 3;
    if ((kt & 7) == 0) {
      miR[k & 1] = midx[(size_t)k * HW_];
      mwR[k & 1] = mwgt[(size_t)k * HW_];
    }
    const int4 mi = miR[k & 1];
    const float* pl = xb + (size_t)((kt & 7) * 32 + cr * 4) * HW_;
#pragma unroll
    for (int i = 0; i < 4; ++i) {
      rg[4 * i + 0] = pl[mi.x];
      rg[4 * i + 1] = pl[mi.y];
      rg[4 * i + 2] = pl[mi.z];
      rg[4 * i + 3] = pl[mi.w];
      pl += HW_;
    }
  };

  auto pack = [&](int kt, const float (&rg)[16], int2& pk) {
    const float4 mw = mwR[(kt >> 3) & 1];
    unsigned bf[4];
#pragma unroll
    for (int i = 0; i < 4; ++i) {
      float v = mw.x * rg[4 * i] + mw.y * rg[4 * i + 1] + mw.z * rg[4 * i + 2] +
                mw.w * rg[4 * i + 3];
      bf[i] = f2bfu(v);
    }
    pk.x = bf[0] | (bf[1] << 16);
    pk.y = bf[2] | (bf[3] << 16);
  };

  const int bslot = (cr >> 1) * 512 + p * 8 + (cr & 1) * 4;

  auto compute = [&](int buf) {
    const int kg = lane >> 4, rr = lane & 15;
    bf16x8 af[4], bfr[2];
#pragma unroll
    for (int fm = 0; fm < 4; ++fm)
      af[fm] = *(const bf16x8*)&Ald[buf][kg * 2048 + (wo * 64 + fm * 16 + rr) * 8];
#pragma unroll
    for (int fn = 0; fn < 2; ++fn)
      bfr[fn] = *(const bf16x8*)&Bld[buf][kg * 512 + (wp * 32 + fn * 16 + rr) * 8];
#pragma unroll
    for (int fm = 0; fm < 4; ++fm)
#pragma unroll
      for (int fn = 0; fn < 2; ++fn)
        acc[fm][fn] = __builtin_amdgcn_mfma_f32_16x16x32_bf16(
            af[fm], bfr[fn], acc[fm][fn], 0, 0, 0);
  };

  float rg0[16], rg1[16];

  // prologue: B(0) immediate, A(0) staged, issue gathers for step 1
  {
    int2 pk;
    issue(0, rg0);
    pack(0, rg0, pk);
    *(int2*)&Bld[0][bslot] = pk;
    stageA(0, 0);
    issue(1, rg1);
  }
  __syncthreads();

  for (int kt = 0; kt < 72; kt += 2) {
    // half A: compute kt (buf0); prepare kt+1 (buf1); issue kt+2 -> rg0
    {
      int2 pk;
      if (kt + 2 < 72) issue(kt + 2, rg0);
      compute(0);
      pack(kt + 1, rg1, pk);
      *(int2*)&Bld[1][bslot] = pk;
      stageA(kt + 1, 1);
      __syncthreads();
    }
    // half B: compute kt+1 (buf1); prepare kt+2 (buf0); issue kt+3 -> rg1
    {
      int2 pk;
      if (kt + 3 < 72) issue(kt + 3, rg1);
      compute(1);
      if (kt + 2 < 72) {
        pack(kt + 2, rg0, pk);
        *(int2*)&Bld[0][bslot] = pk;
        stageA(kt + 2, 0);
      }
      __syncthreads();
    }
  }

  // epilogue: BN + SiLU + store
  const float* bninv = (const float*)(wsb + BN_OFF);
  const float* bnbb = bninv + 256;
  const int rr = lane & 15, rh = lane >> 4;
#pragma unroll
  for (int fm = 0; fm < 4; ++fm) {
#pragma unroll
    for (int r = 0; r < 4; ++r) {
      const int o = wo * 64 + fm * 16 + rh * 4 + r;
      const float inv = bninv[o], bb = bnbb[o];
#pragma unroll
      for (int fn = 0; fn < 2; ++fn) {
        float t = acc[fm][fn][r] * inv + bb;
        float s = t / (1.f + expf(-t));
        out[(size_t)(b * C2_ + o) * HW_ + pt * 64 + wp * 32 + fn * 16 + rr] = s;
      }
    }
  }
}

// ---------------------------------------------------------------------------
extern "C" void kernel_launch(void* const* d_in, const int* in_sizes, int n_in,
                              void* d_out, int out_size, void* d_ws,
                              size_t ws_size, hipStream_t stream) {
  const float* x = (const float*)d_in[0];
  const float* w_om = (const float*)d_in[1];
  const float* b_om = (const float*)d_in[2];
  const float* w_dcn = (const float*)d_in[3];
  const float* bn_gamma = (const float*)d_in[4];
  const float* bn_beta = (const float*)d_in[5];
  const float* bn_mean = (const float*)d_in[6];
  const float* bn_var = (const float*)d_in[7];
  float* out = (float*)d_out;
  char* wsb = (char*)d_ws;

  wom_perm<<<288, 256, 0, stream>>>(w_om, bn_gamma, bn_beta, bn_mean, bn_var,
                                    wsb);
  wt_perm<<<2304, 256, 0, stream>>>(w_dcn, wsb);
  om_gemm<<<B_ * 64, 256, 0, stream>>>(x, b_om, wsb);
  dcn_mfma<<<B_ * 64, 512, 0, stream>>>(x, wsb, out);
}

// Round 6
// 144.138 us; speedup vs baseline: 1.4908x; 1.4908x over previous
//
#include <hip/hip_runtime.h>
#include <math.h>

#define B_  4
#define C1_ 256
#define C2_ 256
#define H_  64
#define W_  64
#define HW_ 4096
#define KK_ 9

// ws byte offsets
#define WA_OFF    0u            // bf16 Wa[72][4][256][8]           (1,179,648 B)
#define XBF_OFF   1179648u      // bf16 xbf[B][C1][HW]              (8,388,608 B)
#define MIDX_OFF  9568256u      // int2  midx[B][9][4096]           (1,179,648 B)
#define MWGT_OFF  10747904u     // float4 mwgt[B][9][4096]          (2,359,296 B)
#define WOM_OFF   13107200u     // bf16 Wom[72][4][32][8]           (147,456 B)
#define BN_OFF    13254656u     // float inv[256]; bb[256]          (2,048 B)

typedef short bf16x8 __attribute__((ext_vector_type(8)));
typedef float f32x4 __attribute__((ext_vector_type(4)));

__device__ __forceinline__ unsigned f2bfu(float f) {
  unsigned u = __builtin_bit_cast(unsigned, f);
  return (u + 0x7FFFu + ((u >> 16) & 1u)) >> 16;
}

__device__ __forceinline__ float bfl(unsigned short u) {
  return __builtin_bit_cast(float, (unsigned)u << 16);
}

__device__ __forceinline__ void gload_lds16(const void* g, void* l) {
  __builtin_amdgcn_global_load_lds(
      (const __attribute__((address_space(1))) unsigned*)g,
      (__attribute__((address_space(3))) unsigned*)l, 16, 0, 0);
}

// XCD-aware decode, grid 256: each XCD owns 32 consecutive rows of ONE batch.
__device__ __forceinline__ void decode_bid256(int bid, int& b, int& h) {
  const int xcd = bid & 7, slot = bid >> 3;
  b = xcd >> 1;
  h = (xcd & 1) * 32 + slot;
}

// grid 512 variant: 2 p-half blocks per row, same row-locality per XCD.
__device__ __forceinline__ void decode_bid512(int bid, int& b, int& h, int& ph) {
  const int xcd = bid & 7, slot = bid >> 3;  // slot < 64
  b = xcd >> 1;
  h = (xcd & 1) * 32 + (slot >> 1);
  ph = slot & 1;
}

// ---------------------------------------------------------------------------
// xcast: x f32 -> bf16 xbf in ws. 4 elems/thread.
// ---------------------------------------------------------------------------
__global__ __launch_bounds__(256) void xcast(const float* __restrict__ x,
                                             char* __restrict__ wsb) {
  const int gid = (blockIdx.x * 256 + threadIdx.x) * 4;
  const float4 v = *(const float4*)(x + gid);
  ushort4 o;
  o.x = (unsigned short)f2bfu(v.x);
  o.y = (unsigned short)f2bfu(v.y);
  o.z = (unsigned short)f2bfu(v.z);
  o.w = (unsigned short)f2bfu(v.w);
  *(ushort4*)((unsigned short*)(wsb + XBF_OFF) + gid) = o;
}

// ---------------------------------------------------------------------------
// wom_perm: w_om [27][C1][9] -> Wom bf16 [72 kt][4 kg][32 o][8 j], ck=k*256+c,
// o padded 27->32 with zeros. Block 0 also precomputes BN inv/bb.
// ---------------------------------------------------------------------------
__global__ __launch_bounds__(256) void wom_perm(
    const float* __restrict__ w_om, const float* __restrict__ bn_gamma,
    const float* __restrict__ bn_beta, const float* __restrict__ bn_mean,
    const float* __restrict__ bn_var, char* __restrict__ wsb) {
  if (blockIdx.x == 0) {
    const int o = threadIdx.x;
    float inv = bn_gamma[o] * rsqrtf(bn_var[o] + 1e-5f);
    ((float*)(wsb + BN_OFF))[o] = inv;
    ((float*)(wsb + BN_OFF))[256 + o] = bn_beta[o] - bn_mean[o] * inv;
  }
  const unsigned e = blockIdx.x * 256 + threadIdx.x;  // < 73728
  const unsigned kt = e >> 10, kg = (e >> 8) & 3, o = (e >> 3) & 31, j = e & 7;
  const unsigned ck = kt * 32 + kg * 8 + j;
  const unsigned k = ck >> 8, c = ck & 255;
  const float v = (o < 27) ? w_om[((size_t)o * C1_ + c) * 9 + k] : 0.f;
  ((unsigned short*)(wsb + WOM_OFF))[e] = (unsigned short)f2bfu(v);
}

// ---------------------------------------------------------------------------
// wt_perm: w_dcn [C2][C1][9] -> Wa bf16 [72 kt][4 kg][256 o][8 j], ck=k*256+c.
// ---------------------------------------------------------------------------
__global__ __launch_bounds__(256) void wt_perm(const float* __restrict__ w_dcn,
                                               char* __restrict__ wsb) {
  const unsigned e = blockIdx.x * 256 + threadIdx.x;  // < 589824
  const unsigned kt = e >> 13, r2 = e & 8191;
  const unsigned kg = r2 >> 11, r3 = r2 & 2047, o = r3 >> 3, j = r3 & 7;
  const unsigned ck = kt * 32 + kg * 8 + j;
  const unsigned k = ck >> 8, c = ck & 255;
  const float v = w_dcn[((size_t)o * C1_ + c) * 9 + k];
  ((unsigned short*)(wsb + WA_OFF))[e] = (unsigned short)f2bfu(v);
}

// ---------------------------------------------------------------------------
// om_gemm: om[oc,p] = sum_ck Wom[ck,oc] * im2col(x)[ck,p] (MFMA), then fused
// epilogue: bias + clamp/sigmoid -> bilinear meta.
// Meta format: midx int2 = (y0c*64+xb, y1c*64+xb) with xb=clamp(x0,0,62);
// mwgt float4 = m * outer({wy0,wy1},{wx0,wx1}) with validity/clamp folded in.
// Block: O=32 x P=64, 256 thr = 4 waves; grid = 256 (XCD-swizzled (b,h)).
// ---------------------------------------------------------------------------
__global__ __launch_bounds__(256) void om_gemm(const float* __restrict__ x,
                                               const float* __restrict__ b_om,
                                               char* __restrict__ wsb) {
  __shared__ short Ald[2][1024];  // [buf][kg4][o32][j8]
  __shared__ short Bld[2][2048];  // [buf][kg4][p64][j8]
  __shared__ float omld[32][65];

  int b, h;
  decode_bid256(blockIdx.x, b, h);
  const int tid = threadIdx.x;
  const int lane = tid & 63, wid = tid >> 6;
  const int wo = wid >> 1, wp = wid & 1;
  const int w = tid & 63;
  const int cr = tid >> 6;

  const unsigned short* Wom = (const unsigned short*)(wsb + WOM_OFF);
  const float* xb_ = x + (size_t)b * C1_ * HW_;

  f32x4 acc[2];
#pragma unroll
  for (int j = 0; j < 2; ++j) acc[j] = (f32x4){0.f, 0.f, 0.f, 0.f};

  auto stageA = [&](int kt, int buf) {
    if (tid < 128)
      gload_lds16((const char*)(Wom + (size_t)kt * 1024) + tid * 16,
                  (char*)&Ald[buf][0] + tid * 16);
  };

  auto produce = [&](int kt, int4& pk) {
    const int k = kt >> 3;
    const int c0 = (kt & 7) * 32 + cr * 8;
    const int hh = h - 1 + k / 3, ww = w - 1 + k % 3;
    const bool v = ((unsigned)hh < (unsigned)H_) && ((unsigned)ww < (unsigned)W_);
    const float* pl = xb_ + (size_t)c0 * HW_ + (v ? hh * W_ + ww : 0);
    unsigned bf[8];
#pragma unroll
    for (int i = 0; i < 8; ++i) {
      float t = v ? pl[(size_t)i * HW_] : 0.f;
      bf[i] = f2bfu(t);
    }
    pk.x = bf[0] | (bf[1] << 16);
    pk.y = bf[2] | (bf[3] << 16);
    pk.z = bf[4] | (bf[5] << 16);
    pk.w = bf[6] | (bf[7] << 16);
  };

  const int bslot = cr * 512 + w * 8;

  auto compute = [&](int buf) {
    const int kg = lane >> 4, rr = lane & 15;
    bf16x8 af = *(const bf16x8*)&Ald[buf][kg * 256 + (wo * 16 + rr) * 8];
#pragma unroll
    for (int fn = 0; fn < 2; ++fn) {
      bf16x8 bfr =
          *(const bf16x8*)&Bld[buf][kg * 512 + (wp * 32 + fn * 16 + rr) * 8];
      acc[fn] = __builtin_amdgcn_mfma_f32_16x16x32_bf16(af, bfr, acc[fn], 0, 0, 0);
    }
  };

  {
    int4 pk;
    stageA(0, 0);
    produce(0, pk);
    *(int4*)&Bld[0][bslot] = pk;
  }
  __syncthreads();

  auto iter = [&](int kt, int buf) {
    const int nxt = buf ^ 1;
    int4 pk;
    const bool pre = (kt < 71);
    if (pre) {
      stageA(kt + 1, nxt);
      produce(kt + 1, pk);
    }
    compute(buf);
    if (pre) *(int4*)&Bld[nxt][bslot] = pk;
    __syncthreads();
  };

  for (int kt = 0; kt < 72; kt += 2) {
    iter(kt, 0);
    iter(kt + 1, 1);
  }

  // stash om tile to LDS (transpose to per-column access)
  {
    const int rr = lane & 15, rh = lane >> 4;
#pragma unroll
    for (int r = 0; r < 4; ++r) {
      const int oc = wo * 16 + rh * 4 + r;
#pragma unroll
      for (int fn = 0; fn < 2; ++fn) {
        const int p = wp * 32 + fn * 16 + rr;
        omld[oc][p] = acc[fn][r];
      }
    }
  }
  __syncthreads();

  // fused om_final: one thread per column p
  if (tid < 64) {
    const int p = tid;
    float a[27];
#pragma unroll
    for (int oc = 0; oc < 27; ++oc) a[oc] = omld[oc][p] + b_om[oc];

    int2* midx = (int2*)(wsb + MIDX_OFF);
    float4* mwgt = (float4*)(wsb + MWGT_OFF);
#pragma unroll
    for (int k = 0; k < 9; ++k) {
      float dy = fminf(fmaxf(a[2 * k], -6.f), 6.f);
      float dx = fminf(fmaxf(a[2 * k + 1], -6.f), 6.f);
      float m = 1.f / (1.f + expf(-a[18 + k]));
      float py = (float)(h - 1 + k / 3) + dy;
      float px = (float)(p - 1 + k % 3) + dx;
      float y0f = floorf(py), x0f = floorf(px);
      float ly = py - y0f, lx = px - x0f;
      int y0 = (int)y0f, x0 = (int)x0f;
      int y1 = y0 + 1, x1 = x0 + 1;
      const bool vy0 = ((unsigned)y0 < (unsigned)H_);
      const bool vy1 = ((unsigned)y1 < (unsigned)H_);
      const bool vx0 = ((unsigned)x0 < (unsigned)W_);
      const bool vx1 = ((unsigned)x1 < (unsigned)W_);
      int y0c = min(max(y0, 0), H_ - 1), y1c = min(max(y1, 0), H_ - 1);
      int x0c = min(max(x0, 0), W_ - 1), x1c = min(max(x1, 0), W_ - 1);
      // base column xb: elements (xb, xb+1) cover both clamped x-corners
      const int xbc = min(max(x0, 0), W_ - 2);
      float wx0 = 0.f, wx1 = 0.f;
      if (vx0) { if (x0c == xbc) wx0 += 1.f - lx; else wx1 += 1.f - lx; }
      if (vx1) { if (x1c == xbc) wx0 += lx; else wx1 += lx; }
      const float wy0 = vy0 ? (1.f - ly) : 0.f;
      const float wy1 = vy1 ? ly : 0.f;
      const size_t e = ((size_t)b * KK_ + k) * HW_ + h * W_ + p;
      midx[e] = make_int2(y0c * W_ + xbc, y1c * W_ + xbc);
      mwgt[e] = make_float4(m * wy0 * wx0, m * wy0 * wx1, m * wy1 * wx0,
                            m * wy1 * wx1);
    }
  }
}

// ---------------------------------------------------------------------------
// dcn_mfma: out[o,p] = sum_ck Wa[ck,o] * col[ck,p], fused BN+SiLU.
// Block: O=256 x P=32, 256 thr = 4 waves (wave 64o x 32p, 4x2 frags).
// grid = 512 (2 blocks/CU for latency overlap), XCD-swizzled (b,h,ph).
// Gathers read bf16 xbf (half the L1 line footprint of f32).
// ---------------------------------------------------------------------------
__global__ __launch_bounds__(256) void dcn_mfma(const char* __restrict__ wsb,
                                                float* __restrict__ out) {
  __shared__ short Ald[2][8192];  // [buf][kg4][o256][j8]
  __shared__ short Bld[2][1024];  // [buf][kg4][p32][j8]

  int b, h, ph;
  decode_bid512(blockIdx.x, b, h, ph);
  const int tid = threadIdx.x;
  const int lane = tid & 63, wid = tid >> 6;
  const int wo = wid;       // wave o-range: 64 o each
  const int p = tid & 31;   // producer column
  const int cr = tid >> 5;  // producer ck-group (4 ch each, 8 groups)

  const unsigned short* Wa = (const unsigned short*)(wsb + WA_OFF);
  const unsigned short* xbf =
      (const unsigned short*)(wsb + XBF_OFF) + (size_t)b * C1_ * HW_;
  const int pg = h * W_ + ph * 32 + p;  // global column
  const int2* midx = (const int2*)(wsb + MIDX_OFF) + (size_t)b * KK_ * HW_ + pg;
  const float4* mwgt =
      (const float4*)(wsb + MWGT_OFF) + (size_t)b * KK_ * HW_ + pg;

  f32x4 acc[4][2];
#pragma unroll
  for (int i = 0; i < 4; ++i)
#pragma unroll
    for (int j = 0; j < 2; ++j) acc[i][j] = (f32x4){0.f, 0.f, 0.f, 0.f};

  int2 mi;
  float4 mw;

  auto stageA = [&](int kt, int buf) {
    const char* src = (const char*)(Wa + (size_t)kt * 8192);
#pragma unroll
    for (int r = 0; r < 4; ++r) {
      const int chunk = r * 256 + tid;
      gload_lds16(src + chunk * 16, (char*)&Ald[buf][0] + chunk * 16);
    }
  };

  // issue gathers for step kt into rg (4 channels x 4 taps, bf16)
  auto issue = [&](int kt, unsigned short (&rg)[16]) {
    const int k = kt >> 3;
    if ((kt & 7) == 0) {
      mi = midx[(size_t)k * HW_];
      mw = mwgt[(size_t)k * HW_];
    }
    const unsigned short* base = xbf + (size_t)((kt & 7) * 32 + cr * 4) * HW_;
#pragma unroll
    for (int i = 0; i < 4; ++i) {
      rg[4 * i + 0] = base[mi.x];
      rg[4 * i + 1] = base[mi.x + 1];
      rg[4 * i + 2] = base[mi.y];
      rg[4 * i + 3] = base[mi.y + 1];
      base += HW_;
    }
  };

  auto pack = [&](const unsigned short (&rg)[16], int2& pk) {
    unsigned bf[4];
#pragma unroll
    for (int i = 0; i < 4; ++i) {
      float v = mw.x * bfl(rg[4 * i]) + mw.y * bfl(rg[4 * i + 1]) +
                mw.z * bfl(rg[4 * i + 2]) + mw.w * bfl(rg[4 * i + 3]);
      bf[i] = f2bfu(v);
    }
    pk.x = bf[0] | (bf[1] << 16);
    pk.y = bf[2] | (bf[3] << 16);
  };

  // thread's 4 ck = cr*4..cr*4+3 -> kg = cr>>1, j0 = (cr&1)*4
  const int bslot = (cr >> 1) * 256 + p * 8 + (cr & 1) * 4;

  auto compute = [&](int buf) {
    const int kg = lane >> 4, rr = lane & 15;
    bf16x8 af[4], bfr[2];
#pragma unroll
    for (int fm = 0; fm < 4; ++fm)
      af[fm] = *(const bf16x8*)&Ald[buf][kg * 2048 + (wo * 64 + fm * 16 + rr) * 8];
#pragma unroll
    for (int fn = 0; fn < 2; ++fn)
      bfr[fn] = *(const bf16x8*)&Bld[buf][kg * 256 + (fn * 16 + rr) * 8];
#pragma unroll
    for (int fm = 0; fm < 4; ++fm)
#pragma unroll
      for (int fn = 0; fn < 2; ++fn)
        acc[fm][fn] = __builtin_amdgcn_mfma_f32_16x16x32_bf16(
            af[fm], bfr[fn], acc[fm][fn], 0, 0, 0);
  };

  unsigned short rg[16];

  // prologue: B(0) + A(0) into buf 0
  {
    int2 pk;
    issue(0, rg);
    pack(rg, pk);
    *(int2*)&Bld[0][bslot] = pk;
    stageA(0, 0);
  }
  __syncthreads();

  for (int kt = 0; kt < 72; ++kt) {
    const int cur = kt & 1, nxt = cur ^ 1;
    const bool pre = (kt < 71);
    if (pre) {
      issue(kt + 1, rg);   // gathers in flight during compute
      stageA(kt + 1, nxt);
    }
    compute(cur);
    if (pre) {
      int2 pk;
      pack(rg, pk);
      *(int2*)&Bld[nxt][bslot] = pk;
    }
    __syncthreads();
  }

  // epilogue: BN + SiLU + store
  const float* bninv = (const float*)(wsb + BN_OFF);
  const float* bnbb = bninv + 256;
  const int rr = lane & 15, rh = lane >> 4;
#pragma unroll
  for (int fm = 0; fm < 4; ++fm) {
#pragma unroll
    for (int r = 0; r < 4; ++r) {
      const int o = wo * 64 + fm * 16 + rh * 4 + r;
      const float inv = bninv[o], bb = bnbb[o];
#pragma unroll
      for (int fn = 0; fn < 2; ++fn) {
        float t = acc[fm][fn][r] * inv + bb;
        float s = t / (1.f + expf(-t));
        out[(size_t)(b * C2_ + o) * HW_ + h * W_ + ph * 32 + fn * 16 + rr] = s;
      }
    }
  }
}

// ---------------------------------------------------------------------------
extern "C" void kernel_launch(void* const* d_in, const int* in_sizes, int n_in,
                              void* d_out, int out_size, void* d_ws,
                              size_t ws_size, hipStream_t stream) {
  const float* x = (const float*)d_in[0];
  const float* w_om = (const float*)d_in[1];
  const float* b_om = (const float*)d_in[2];
  const float* w_dcn = (const float*)d_in[3];
  const float* bn_gamma = (const float*)d_in[4];
  const float* bn_beta = (const float*)d_in[5];
  const float* bn_mean = (const float*)d_in[6];
  const float* bn_var = (const float*)d_in[7];
  float* out = (float*)d_out;
  char* wsb = (char*)d_ws;

  xcast<<<4096, 256, 0, stream>>>(x, wsb);
  wom_perm<<<288, 256, 0, stream>>>(w_om, bn_gamma, bn_beta, bn_mean, bn_var,
                                    wsb);
  wt_perm<<<2304, 256, 0, stream>>>(w_dcn, wsb);
  om_gemm<<<B_ * 64, 256, 0, stream>>>(x, b_om, wsb);
  dcn_mfma<<<B_ * 64 * 2, 256, 0, stream>>>(wsb, out);
}

// Round 7
// 135.042 us; speedup vs baseline: 1.5912x; 1.0674x over previous
//
#include <hip/hip_runtime.h>
#include <math.h>

#define B_  4
#define C1_ 256
#define C2_ 256
#define H_  64
#define W_  64
#define HW_ 4096
#define KK_ 9

// ws byte offsets
#define WA_OFF    0u            // bf16 Wa[72][4][256][8]           (1,179,648 B)
#define XBF_OFF   1179648u      // bf16 xbf[B][C1][HW]              (8,388,608 B)
#define MIDX_OFF  9568256u      // int2  midx[B][9][4096]           (1,179,648 B)
#define MWGT_OFF  10747904u     // float4 mwgt[B][9][4096]          (2,359,296 B)
#define WOM_OFF   13107200u     // bf16 Wom[72][4][32][8]           (147,456 B)
#define BN_OFF    13254656u     // float inv[256]; bb[256]          (2,048 B)

typedef short bf16x8 __attribute__((ext_vector_type(8)));
typedef float f32x4 __attribute__((ext_vector_type(4)));

__device__ __forceinline__ unsigned f2bfu(float f) {
  unsigned u = __builtin_bit_cast(unsigned, f);
  return (u + 0x7FFFu + ((u >> 16) & 1u)) >> 16;
}

__device__ __forceinline__ float bfl(unsigned short u) {
  return __builtin_bit_cast(float, (unsigned)u << 16);
}

__device__ __forceinline__ void gload_lds16(const void* g, void* l) {
  __builtin_amdgcn_global_load_lds(
      (const __attribute__((address_space(1))) unsigned*)g,
      (__attribute__((address_space(3))) unsigned*)l, 16, 0, 0);
}

// grid 512: 8 XCDs; each XCD owns 32 consecutive rows of ONE batch
// (x slice ~2.6 MB incl. halo fits per-XCD 4 MB L2). ph = p-half of row.
__device__ __forceinline__ void decode_bid512(int bid, int& b, int& h, int& ph) {
  const int xcd = bid & 7, slot = bid >> 3;  // slot < 64
  b = xcd >> 1;
  h = (xcd & 1) * 32 + (slot >> 1);
  ph = slot & 1;
}

// ---------------------------------------------------------------------------
// prep: fused xcast (blocks 0..2047) + wt_perm (2048..4351) + wom_perm/BN
// (4352..4639). One launch instead of three.
// ---------------------------------------------------------------------------
__global__ __launch_bounds__(256) void prep(
    const float* __restrict__ x, const float* __restrict__ w_om,
    const float* __restrict__ w_dcn, const float* __restrict__ bn_gamma,
    const float* __restrict__ bn_beta, const float* __restrict__ bn_mean,
    const float* __restrict__ bn_var, char* __restrict__ wsb) {
  const int bid = blockIdx.x;
  if (bid < 2048) {
    // xcast: 8 f32 -> bf16 per thread
    const int gid = (bid * 256 + threadIdx.x) * 8;
    const float4 v0 = *(const float4*)(x + gid);
    const float4 v1 = *(const float4*)(x + gid + 4);
    int4 o;
    o.x = f2bfu(v0.x) | (f2bfu(v0.y) << 16);
    o.y = f2bfu(v0.z) | (f2bfu(v0.w) << 16);
    o.z = f2bfu(v1.x) | (f2bfu(v1.y) << 16);
    o.w = f2bfu(v1.z) | (f2bfu(v1.w) << 16);
    *(int4*)((unsigned short*)(wsb + XBF_OFF) + gid) = o;
  } else if (bid < 2048 + 2304) {
    // wt_perm: w_dcn [C2][C1][9] -> Wa bf16 [72][4][256][8], ck=k*256+c
    const unsigned e = (bid - 2048) * 256 + threadIdx.x;  // < 589824
    const unsigned kt = e >> 13, r2 = e & 8191;
    const unsigned kg = r2 >> 11, r3 = r2 & 2047, o = r3 >> 3, j = r3 & 7;
    const unsigned ck = kt * 32 + kg * 8 + j;
    const unsigned k = ck >> 8, c = ck & 255;
    const float v = w_dcn[((size_t)o * C1_ + c) * 9 + k];
    ((unsigned short*)(wsb + WA_OFF))[e] = (unsigned short)f2bfu(v);
  } else {
    const int wb = bid - (2048 + 2304);
    if (wb == 0) {
      const int o = threadIdx.x;
      float inv = bn_gamma[o] * rsqrtf(bn_var[o] + 1e-5f);
      ((float*)(wsb + BN_OFF))[o] = inv;
      ((float*)(wsb + BN_OFF))[256 + o] = bn_beta[o] - bn_mean[o] * inv;
    }
    // wom_perm: w_om [27][C1][9] -> Wom bf16 [72][4][32][8], o padded to 32
    const unsigned e = wb * 256 + threadIdx.x;  // < 73728
    const unsigned kt = e >> 10, kg = (e >> 8) & 3, o = (e >> 3) & 31, j = e & 7;
    const unsigned ck = kt * 32 + kg * 8 + j;
    const unsigned k = ck >> 8, c = ck & 255;
    const float v = (o < 27) ? w_om[((size_t)o * C1_ + c) * 9 + k] : 0.f;
    ((unsigned short*)(wsb + WOM_OFF))[e] = (unsigned short)f2bfu(v);
  }
}

// ---------------------------------------------------------------------------
// om_gemm: om[oc,p] = sum_ck Wom[ck,oc] * im2col(xbf)[ck,p] (MFMA) + fused
// epilogue (bias + clamp/sigmoid -> bilinear meta: midx int2 base-column
// scheme, mwgt premultiplied outer-product weights).
// Block: O=32 x P=32, 256 thr = 4 waves (wave 16x16); BK=64, 36 steps.
// grid = 512 (2 blocks/CU), XCD-swizzled (b,h,ph).
// ---------------------------------------------------------------------------
__global__ __launch_bounds__(256) void om_gemm(const float* __restrict__ b_om,
                                               char* __restrict__ wsb) {
  __shared__ short Ald[2][2048];  // [buf][kh2][kg4][o32][j8]
  __shared__ short Bld[2][2048];  // [buf][kh2][kg4][p32][j8]
  __shared__ float omld[32][33];

  int b, h, ph;
  decode_bid512(blockIdx.x, b, h, ph);
  const int tid = threadIdx.x;
  const int lane = tid & 63, wid = tid >> 6;
  const int wo = wid >> 1, wp = wid & 1;
  const int p = tid & 31;
  const int cr = tid >> 5;  // 8 groups x 8 ck

  const unsigned short* Wom = (const unsigned short*)(wsb + WOM_OFF);
  const unsigned short* xbf =
      (const unsigned short*)(wsb + XBF_OFF) + (size_t)b * C1_ * HW_;

  f32x4 acc = (f32x4){0.f, 0.f, 0.f, 0.f};

  auto stageA = [&](int s, int buf) {
    gload_lds16((const char*)(Wom + (size_t)s * 2048) + tid * 16,
                (char*)&Ald[buf][0] + tid * 16);
  };

  auto produce = [&](int s, int4& pk) {
    const int k = s >> 2;
    const int c0 = (s & 3) * 64 + cr * 8;
    const int hh = h - 1 + k / 3;
    const int ww = ph * 32 + p - 1 + k % 3;
    const bool v = ((unsigned)hh < (unsigned)H_) && ((unsigned)ww < (unsigned)W_);
    const unsigned short* pl = xbf + (size_t)c0 * HW_ + (v ? hh * W_ + ww : 0);
    unsigned u[8];
#pragma unroll
    for (int i = 0; i < 8; ++i) u[i] = v ? (unsigned)pl[(size_t)i * HW_] : 0u;
    pk.x = u[0] | (u[1] << 16);
    pk.y = u[2] | (u[3] << 16);
    pk.z = u[4] | (u[5] << 16);
    pk.w = u[6] | (u[7] << 16);
  };

  // kk = cr*8 + i -> khalf = cr>>2, kg = cr&3, j = i
  const int bslot = (cr >> 2) * 1024 + (cr & 3) * 256 + p * 8;

  auto compute = [&](int buf) {
    const int kg = lane >> 4, rr = lane & 15;
#pragma unroll
    for (int kh = 0; kh < 2; ++kh) {
      bf16x8 af = *(const bf16x8*)&Ald[buf][kh * 1024 + kg * 256 + (wo * 16 + rr) * 8];
      bf16x8 bfr = *(const bf16x8*)&Bld[buf][kh * 1024 + kg * 256 + (wp * 16 + rr) * 8];
      acc = __builtin_amdgcn_mfma_f32_16x16x32_bf16(af, bfr, acc, 0, 0, 0);
    }
  };

  {
    int4 pk;
    produce(0, pk);
    *(int4*)&Bld[0][bslot] = pk;
    stageA(0, 0);
  }
  __syncthreads();

  for (int s = 0; s < 36; ++s) {
    const int cur = s & 1, nxt = cur ^ 1;
    const bool pre = (s < 35);
    int4 pk;
    if (pre) {
      produce(s + 1, pk);
      stageA(s + 1, nxt);
    }
    compute(cur);
    if (pre) *(int4*)&Bld[nxt][bslot] = pk;
    __syncthreads();
  }

  // stash om tile to LDS (transpose)
  {
    const int rr = lane & 15, rh = lane >> 4;
#pragma unroll
    for (int r = 0; r < 4; ++r) {
      const int oc = wo * 16 + rh * 4 + r;
      omld[oc][wp * 16 + rr] = acc[r];
    }
  }
  __syncthreads();

  // fused om_final: one thread per column
  if (tid < 32) {
    const int pc = tid;
    float a[27];
#pragma unroll
    for (int oc = 0; oc < 27; ++oc) a[oc] = omld[oc][pc] + b_om[oc];

    int2* midx = (int2*)(wsb + MIDX_OFF);
    float4* mwgt = (float4*)(wsb + MWGT_OFF);
    const int pcol = ph * 32 + pc;
#pragma unroll
    for (int k = 0; k < 9; ++k) {
      float dy = fminf(fmaxf(a[2 * k], -6.f), 6.f);
      float dx = fminf(fmaxf(a[2 * k + 1], -6.f), 6.f);
      float m = 1.f / (1.f + expf(-a[18 + k]));
      float py = (float)(h - 1 + k / 3) + dy;
      float px = (float)(pcol - 1 + k % 3) + dx;
      float y0f = floorf(py), x0f = floorf(px);
      float ly = py - y0f, lx = px - x0f;
      int y0 = (int)y0f, x0 = (int)x0f;
      int y1 = y0 + 1, x1 = x0 + 1;
      const bool vy0 = ((unsigned)y0 < (unsigned)H_);
      const bool vy1 = ((unsigned)y1 < (unsigned)H_);
      const bool vx0 = ((unsigned)x0 < (unsigned)W_);
      const bool vx1 = ((unsigned)x1 < (unsigned)W_);
      int y0c = min(max(y0, 0), H_ - 1), y1c = min(max(y1, 0), H_ - 1);
      int x0c = min(max(x0, 0), W_ - 1), x1c = min(max(x1, 0), W_ - 1);
      const int xbc = min(max(x0, 0), W_ - 2);
      float wx0 = 0.f, wx1 = 0.f;
      if (vx0) { if (x0c == xbc) wx0 += 1.f - lx; else wx1 += 1.f - lx; }
      if (vx1) { if (x1c == xbc) wx0 += lx; else wx1 += lx; }
      const float wy0 = vy0 ? (1.f - ly) : 0.f;
      const float wy1 = vy1 ? ly : 0.f;
      const size_t e = ((size_t)b * KK_ + k) * HW_ + h * W_ + pcol;
      midx[e] = make_int2(y0c * W_ + xbc, y1c * W_ + xbc);
      mwgt[e] = make_float4(m * wy0 * wx0, m * wy0 * wx1, m * wy1 * wx0,
                            m * wy1 * wx1);
    }
  }
}

// ---------------------------------------------------------------------------
// dcn_mfma: out[o,p] = sum_ck Wa[ck,o] * col[ck,p], fused BN+SiLU.
// Block: O=256 x P=32, 512 thr = 8 waves (wave 32o x 32p, 2x2 frags).
// BK=64: 36 steps, double-buffered LDS (72 KB -> 2 blocks/CU = 16 waves/CU).
// grid = 512, XCD-swizzled (b,h,ph). Gathers read bf16 xbf.
// ---------------------------------------------------------------------------
__global__ __launch_bounds__(512, 4) void dcn_mfma(const char* __restrict__ wsb,
                                                   float* __restrict__ out) {
  __shared__ short Ald[2][16384];  // [buf][kh2][kg4][o256][j8] (32 KB/buf)
  __shared__ short Bld[2][2048];   // [buf][kh2][kg4][p32][j8]

  int b, h, ph;
  decode_bid512(blockIdx.x, b, h, ph);
  const int tid = threadIdx.x;
  const int lane = tid & 63, wid = tid >> 6;  // wid 0..7: o-range 32 each
  const int p = tid & 31;
  const int cr = tid >> 5;  // 16 groups x 4 ck

  const unsigned short* Wa = (const unsigned short*)(wsb + WA_OFF);
  const unsigned short* xbf =
      (const unsigned short*)(wsb + XBF_OFF) + (size_t)b * C1_ * HW_;
  const int pg = h * W_ + ph * 32 + p;
  const int2* midx = (const int2*)(wsb + MIDX_OFF) + (size_t)b * KK_ * HW_ + pg;
  const float4* mwgt =
      (const float4*)(wsb + MWGT_OFF) + (size_t)b * KK_ * HW_ + pg;

  f32x4 acc[2][2];
#pragma unroll
  for (int i = 0; i < 2; ++i)
#pragma unroll
    for (int j = 0; j < 2; ++j) acc[i][j] = (f32x4){0.f, 0.f, 0.f, 0.f};

  int2 mi;
  float4 mw;

  auto stageA = [&](int s, int buf) {
    const char* src = (const char*)(Wa + (size_t)s * 16384);
#pragma unroll
    for (int r = 0; r < 4; ++r) {
      const int chunk = r * 512 + tid;
      gload_lds16(src + chunk * 16, (char*)&Ald[buf][0] + chunk * 16);
    }
  };

  // issue gathers for step s into rg (4 channels x 4 taps, bf16)
  auto issue = [&](int s, unsigned short (&rg)[16]) {
    const int k = s >> 2;
    if ((s & 3) == 0) {
      mi = midx[(size_t)k * HW_];
      mw = mwgt[(size_t)k * HW_];
    }
    const unsigned short* base = xbf + (size_t)((s & 3) * 64 + cr * 4) * HW_;
#pragma unroll
    for (int i = 0; i < 4; ++i) {
      rg[4 * i + 0] = base[mi.x];
      rg[4 * i + 1] = base[mi.x + 1];
      rg[4 * i + 2] = base[mi.y];
      rg[4 * i + 3] = base[mi.y + 1];
      base += HW_;
    }
  };

  auto pack = [&](const unsigned short (&rg)[16], int2& pk) {
    unsigned bf[4];
#pragma unroll
    for (int i = 0; i < 4; ++i) {
      float v = mw.x * bfl(rg[4 * i]) + mw.y * bfl(rg[4 * i + 1]) +
                mw.z * bfl(rg[4 * i + 2]) + mw.w * bfl(rg[4 * i + 3]);
      bf[i] = f2bfu(v);
    }
    pk.x = bf[0] | (bf[1] << 16);
    pk.y = bf[2] | (bf[3] << 16);
  };

  // kk = cr*4 + i -> khalf = cr>>3, kg = (cr>>1)&3, j0 = (cr&1)*4
  const int bslot = (cr >> 3) * 1024 + ((cr >> 1) & 3) * 256 + p * 8 + (cr & 1) * 4;

  auto compute = [&](int buf) {
    const int kg = lane >> 4, rr = lane & 15;
    bf16x8 af[2][2], bfr[2][2];
#pragma unroll
    for (int kh = 0; kh < 2; ++kh) {
#pragma unroll
      for (int fm = 0; fm < 2; ++fm)
        af[fm][kh] = *(const bf16x8*)&Ald[buf][kh * 8192 + kg * 2048 +
                                              (wid * 32 + fm * 16 + rr) * 8];
#pragma unroll
      for (int fn = 0; fn < 2; ++fn)
        bfr[fn][kh] =
            *(const bf16x8*)&Bld[buf][kh * 1024 + kg * 256 + (fn * 16 + rr) * 8];
    }
#pragma unroll
    for (int kh = 0; kh < 2; ++kh)
#pragma unroll
      for (int fm = 0; fm < 2; ++fm)
#pragma unroll
        for (int fn = 0; fn < 2; ++fn)
          acc[fm][fn] = __builtin_amdgcn_mfma_f32_16x16x32_bf16(
              af[fm][kh], bfr[fn][kh], acc[fm][fn], 0, 0, 0);
  };

  unsigned short rg[16];

  // prologue
  {
    int2 pk;
    issue(0, rg);
    pack(rg, pk);
    *(int2*)&Bld[0][bslot] = pk;
    stageA(0, 0);
  }
  __syncthreads();

  for (int s = 0; s < 36; ++s) {
    const int cur = s & 1, nxt = cur ^ 1;
    const bool pre = (s < 35);
    if (pre) {
      issue(s + 1, rg);  // gathers in flight during compute
      stageA(s + 1, nxt);
    }
    compute(cur);
    if (pre) {
      int2 pk;
      pack(rg, pk);
      *(int2*)&Bld[nxt][bslot] = pk;
    }
    __syncthreads();
  }

  // epilogue: BN + SiLU + store
  const float* bninv = (const float*)(wsb + BN_OFF);
  const float* bnbb = bninv + 256;
  const int rr = lane & 15, rh = lane >> 4;
#pragma unroll
  for (int fm = 0; fm < 2; ++fm) {
#pragma unroll
    for (int r = 0; r < 4; ++r) {
      const int o = wid * 32 + fm * 16 + rh * 4 + r;
      const float inv = bninv[o], bb = bnbb[o];
#pragma unroll
      for (int fn = 0; fn < 2; ++fn) {
        float t = acc[fm][fn][r] * inv + bb;
        float s = t / (1.f + expf(-t));
        out[(size_t)(b * C2_ + o) * HW_ + h * W_ + ph * 32 + fn * 16 + rr] = s;
      }
    }
  }
}

// ---------------------------------------------------------------------------
extern "C" void kernel_launch(void* const* d_in, const int* in_sizes, int n_in,
                              void* d_out, int out_size, void* d_ws,
                              size_t ws_size, hipStream_t stream) {
  const float* x = (const float*)d_in[0];
  const float* w_om = (const float*)d_in[1];
  const float* b_om = (const float*)d_in[2];
  const float* w_dcn = (const float*)d_in[3];
  const float* bn_gamma = (const float*)d_in[4];
  const float* bn_beta = (const float*)d_in[5];
  const float* bn_mean = (const float*)d_in[6];
  const float* bn_var = (const float*)d_in[7];
  float* out = (float*)d_out;
  char* wsb = (char*)d_ws;

  prep<<<2048 + 2304 + 288, 256, 0, stream>>>(x, w_om, w_dcn, bn_gamma,
                                              bn_beta, bn_mean, bn_var, wsb);
  om_gemm<<<512, 256, 0, stream>>>(b_om, wsb);
  dcn_mfma<<<512, 512, 0, stream>>>(wsb, out);
}